// Round 5
// baseline (2199.539 us; speedup 1.0000x reference)
//
#include <hip/hip_runtime.h>
#include <hip/hip_bf16.h>
#include <cstdint>
#include <cstddef>

// ---------------------------------------------------------------------------
// AutoEncoder: x[8192,1024] -> enc(1024->2048->2048->64, relu/relu/sigmoid)
//             -> dec(64->2048->2048->1024, relu/relu/none)
// R5: ONE persistent fused kernel (1024 blocks), manual device-scope grid
// barrier between the 8 phases (prep, e1, e2, e3-splitK, e3-reduce, d1, d2,
// d3). Removes ~74us of inter-dispatch gaps measured in R3's phase arithmetic.
// GEMM core = R3's best config (128x128 tile, wave 64x64, BK=32, dbuf
// global_load_lds, LDS chunk swizzle -> 0 bank conflicts, XCD M-band swizzle).
// d3 re-tiled 64x128 so it uses all 1024 blocks (was 512). R4's smaller-tile
// experiment falsified the occupancy theory: reverted.
// ---------------------------------------------------------------------------

typedef __bf16 bf16_t;
typedef bf16_t bf16x8 __attribute__((ext_vector_type(8)));
typedef bf16_t bf16x4 __attribute__((ext_vector_type(4)));
typedef float  floatx4 __attribute__((ext_vector_type(4)));

#define NBLK 1024

__device__ __forceinline__ void async_cp16(const bf16_t* gp, bf16_t* lp) {
    __builtin_amdgcn_global_load_lds(
        (const __attribute__((address_space(1))) void*)gp,
        (__attribute__((address_space(3))) void*)lp, 16, 0, 0);
}

// Two-level grid barrier: 32 groups x 32 blocks. grp[] counters at 64B
// stride, root counter, gen word. All zeroed by hipMemsetAsync pre-launch.
// Happens-before: arrivals release prior writes (ACQ_REL RMW chain), final
// leader releases gen; pollers acquire gen.
__device__ __forceinline__ void grid_sync(unsigned* grp, unsigned* root,
                                          unsigned* gen, unsigned s) {
    __syncthreads();
    if (threadIdx.x == 0) {
        __threadfence();
        const int g = blockIdx.x >> 5;
        unsigned a = __hip_atomic_fetch_add(&grp[g * 16], 1u, __ATOMIC_ACQ_REL,
                                            __HIP_MEMORY_SCOPE_AGENT);
        if (a == 31u) {
            __hip_atomic_store(&grp[g * 16], 0u, __ATOMIC_RELAXED,
                               __HIP_MEMORY_SCOPE_AGENT);
            unsigned r = __hip_atomic_fetch_add(root, 1u, __ATOMIC_ACQ_REL,
                                                __HIP_MEMORY_SCOPE_AGENT);
            if (r == 31u) {
                __hip_atomic_store(root, 0u, __ATOMIC_RELAXED,
                                   __HIP_MEMORY_SCOPE_AGENT);
                __hip_atomic_store(gen, s, __ATOMIC_RELEASE,
                                   __HIP_MEMORY_SCOPE_AGENT);
            }
        }
        while (__hip_atomic_load(gen, __ATOMIC_ACQUIRE,
                                 __HIP_MEMORY_SCOPE_AGENT) < s)
            __builtin_amdgcn_s_sleep(2);
    }
    __syncthreads();
}

// 32x32 transpose+cast tile, flat 256 threads (tx=t&31, ty=t>>5)
__device__ __forceinline__ void trans_tile(const float* __restrict__ in,
                                           bf16_t* __restrict__ out,
                                           int K, int N, int bx, int by,
                                           int tx, int ty,
                                           float (*tile)[33]) {
    const int n0 = bx * 32, k0 = by * 32;
#pragma unroll
    for (int i = 0; i < 32; i += 8)
        tile[ty + i][tx] = in[(size_t)(k0 + ty + i) * N + n0 + tx];
    __syncthreads();
#pragma unroll
    for (int i = 0; i < 32; i += 8)
        out[(size_t)(n0 + ty + i) * K + k0 + tx] = (bf16_t)tile[tx][ty + i];
    __syncthreads();
}

// ---------------------------------------------------------------------------
// One GEMM tile: C[m0:m0+BM, n0:n0+BN] = act(A @ Bt^T + bias) over K from kz0.
// OMODE bit0: bf16 out, bit1: f32 out, bit2: f32 split-K partial at Cf[pofs+.]
// ACT: 0 none, 1 relu, 2 sigmoid. lds: >= 2*(BM+BN)*32 bf16.
// ---------------------------------------------------------------------------
template<int BM, int BN, int WM, int WN, int ACT, int OMODE>
__device__ void gemm_tile(const bf16_t* __restrict__ A,
                          const bf16_t* __restrict__ Bt,
                          const float* __restrict__ bias,
                          bf16_t* __restrict__ Cb, float* __restrict__ Cf,
                          int N, int K, int ld, int m0, int n0, int kz0,
                          size_t pofs, bf16_t* lds) {
    constexpr int BK = 32;
    constexpr int MI = WM / 16, NI = WN / 16;
    constexpr int WCOLS = BN / WN;
    static_assert((BM / WM) * (BN / WN) == 4, "4 waves");
    constexpr int A_CPW = (BM * BK) / (8 * 64 * 4);
    constexpr int B_CPW = (BN * BK) / (8 * 64 * 4);
    constexpr int ASZ = BM * BK, BSZ = BN * BK;
    bf16_t* As = lds;
    bf16_t* Bs = lds + 2 * ASZ;

    const int tid  = threadIdx.x;
    const int wave = tid >> 6;
    const int lane = tid & 63;
    const int wm0 = (wave / WCOLS) * WM;
    const int wn0 = (wave % WCOLS) * WN;
    const int r15 = lane & 15;
    const int kgc = lane >> 4;

    floatx4 acc[MI][NI];
#pragma unroll
    for (int i = 0; i < MI; ++i)
#pragma unroll
        for (int j = 0; j < NI; ++j)
            acc[i][j] = floatx4{0.f, 0.f, 0.f, 0.f};

    const bf16_t* a_src[A_CPW];
    int a_dst[A_CPW];
#pragma unroll
    for (int i = 0; i < A_CPW; ++i) {
        const int cbase = (wave * A_CPW + i) * 64;
        const int chunk = cbase + lane;
        const int row = chunk >> 2;
        const int c8  = (((chunk & 3) - (row >> 1)) & 3) * 8;
        a_src[i] = A + (size_t)(m0 + row) * ld + kz0 + c8;
        a_dst[i] = cbase * 8;
    }
    const bf16_t* b_src[B_CPW];
    int b_dst[B_CPW];
#pragma unroll
    for (int i = 0; i < B_CPW; ++i) {
        const int cbase = (wave * B_CPW + i) * 64;
        const int chunk = cbase + lane;
        const int row = chunk >> 2;
        const int c8  = (((chunk & 3) - (row >> 1)) & 3) * 8;
        b_src[i] = Bt + (size_t)(n0 + row) * ld + kz0 + c8;
        b_dst[i] = cbase * 8;
    }
    int a_off[MI], b_off[NI];
#pragma unroll
    for (int i = 0; i < MI; ++i) {
        const int r = wm0 + i * 16 + r15;
        a_off[i] = r * BK + (((kgc + (r >> 1)) & 3) << 3);
    }
#pragma unroll
    for (int j = 0; j < NI; ++j) {
        const int r = wn0 + j * 16 + r15;
        b_off[j] = r * BK + (((kgc + (r >> 1)) & 3) << 3);
    }

    const int nIter = K / BK;
#pragma unroll
    for (int i = 0; i < A_CPW; ++i) async_cp16(a_src[i], As + a_dst[i]);
#pragma unroll
    for (int i = 0; i < B_CPW; ++i) async_cp16(b_src[i], Bs + b_dst[i]);

    for (int it = 0; it < nIter; ++it) {
        __syncthreads();
        if (it + 1 < nIter) {
            const int kn = (it + 1) * BK;
            const int nb = (it + 1) & 1;
#pragma unroll
            for (int i = 0; i < A_CPW; ++i)
                async_cp16(a_src[i] + kn, As + nb * ASZ + a_dst[i]);
#pragma unroll
            for (int i = 0; i < B_CPW; ++i)
                async_cp16(b_src[i] + kn, Bs + nb * BSZ + b_dst[i]);
        }
        const bf16_t* curA = As + (it & 1) * ASZ;
        const bf16_t* curB = Bs + (it & 1) * BSZ;

        bf16x8 af[MI], bfr[NI];
#pragma unroll
        for (int i = 0; i < MI; ++i)
            af[i] = *(const bf16x8*)(curA + a_off[i]);
#pragma unroll
        for (int j = 0; j < NI; ++j)
            bfr[j] = *(const bf16x8*)(curB + b_off[j]);
#pragma unroll
        for (int i = 0; i < MI; ++i)
#pragma unroll
            for (int j = 0; j < NI; ++j)
                acc[i][j] = __builtin_amdgcn_mfma_f32_16x16x32_bf16(
                    af[i], bfr[j], acc[i][j], 0, 0, 0);
    }
    __syncthreads();   // all waves done with LDS before next phase reuses it

    const int row_l = (lane >> 4) * 4;
#pragma unroll
    for (int j = 0; j < NI; ++j) {
        const int n = n0 + wn0 + j * 16 + r15;
        const float bv = (OMODE & 4) ? 0.f : bias[n];
#pragma unroll
        for (int i = 0; i < MI; ++i) {
            const int m = m0 + wm0 + i * 16 + row_l;
#pragma unroll
            for (int r = 0; r < 4; ++r) {
                float f = acc[i][j][r] + bv;
                if (ACT == 1) f = fmaxf(f, 0.f);
                if (ACT == 2) f = 1.f / (1.f + __expf(-f));
                const size_t idx = (size_t)(m + r) * N + n;
                if (OMODE & 1) Cb[idx] = (bf16_t)f;
                if (OMODE & 2) Cf[idx] = f;
                if (OMODE & 4) Cf[pofs + idx] = f;
            }
        }
    }
}

struct FusedArgs {
    const float* x;
    const float* W[6];
    const float* b[6];       // be1,be2,be3,bd1,bd2,bd3
    bf16_t* xb;
    bf16_t* t[6];            // transposed bf16 weights
    bf16_t* ha; bf16_t* hb; bf16_t* cb;
    float* e3part;
    float* out0; float* out1;
    unsigned* bar;           // grp[0..511:16], root@512, gen@528
};

__global__ __launch_bounds__(256, 5) void fused(FusedArgs a) {
    __shared__ bf16_t lds[2 * (128 + 128) * 32];   // 32 KB
    unsigned* grp  = a.bar;
    unsigned* root = a.bar + 512;
    unsigned* gen  = a.bar + 528;
    const int blk = blockIdx.x;
    const int tid = threadIdx.x;

    // ---- P0: prep (x cast + 6 weight transpose+casts) ----
    {
        float (*tile)[33] = (float(*)[33])lds;
        const int tx = tid & 31, ty = tid >> 5;
        for (int u = blk; u < 20736; u += NBLK) {
            if (u < 8192) {
                const int i = (u * 256 + tid) * 4;
                const float4 v = *(const float4*)(a.x + i);
                bf16x4 o;
                o[0] = (bf16_t)v.x; o[1] = (bf16_t)v.y;
                o[2] = (bf16_t)v.z; o[3] = (bf16_t)v.w;
                *(bf16x4*)(a.xb + i) = o;
                continue;
            }
            int lb = u - 8192;
            if (lb < 2048)      { trans_tile(a.W[0], a.t[0], 1024, 2048, lb % 64, lb / 64, tx, ty, tile); continue; }
            lb -= 2048;
            if (lb < 4096)      { trans_tile(a.W[1], a.t[1], 2048, 2048, lb % 64, lb / 64, tx, ty, tile); continue; }
            lb -= 4096;
            if (lb < 128)       { trans_tile(a.W[2], a.t[2], 2048, 64,   lb % 2,  lb / 2,  tx, ty, tile); continue; }
            lb -= 128;
            if (lb < 128)       { trans_tile(a.W[3], a.t[3], 64,   2048, lb % 64, lb / 64, tx, ty, tile); continue; }
            lb -= 128;
            if (lb < 4096)      { trans_tile(a.W[4], a.t[4], 2048, 2048, lb % 64, lb / 64, tx, ty, tile); continue; }
            lb -= 4096;
            trans_tile(a.W[5], a.t[5], 2048, 1024, lb % 32, lb / 32, tx, ty, tile);
        }
    }
    grid_sync(grp, root, gen, 1);

    // XCD swizzle decode for 64 M-rows x 16 N-cols phases
    const int xcd = blk & 7;
    const int loc = blk >> 3;

    // ---- P1: e1 relu(x @ We1) M=8192 K=1024 N=2048 ----
    gemm_tile<128, 128, 64, 64, 1, 1>(
        a.xb, a.t[0], a.b[0], a.ha, nullptr, 2048, 1024, 1024,
        (xcd * 8 + loc / 16) * 128, (loc % 16) * 128, 0, 0, lds);
    grid_sync(grp, root, gen, 2);

    // ---- P2: e2 relu(ha @ We2) K=2048 N=2048 ----
    gemm_tile<128, 128, 64, 64, 1, 1>(
        a.ha, a.t[1], a.b[1], a.hb, nullptr, 2048, 2048, 2048,
        (xcd * 8 + loc / 16) * 128, (loc % 16) * 128, 0, 0, lds);
    grid_sync(grp, root, gen, 3);

    // ---- P3: e3 split-K x16 partials: hb @ We3, K-seg 128 ----
    gemm_tile<128, 64, 32, 64, 0, 4>(
        a.hb, a.t[2], nullptr, nullptr, a.e3part, 64, 128, 2048,
        (blk >> 4) * 128, 0, (blk & 15) * 128,
        (size_t)(blk & 15) * (8192 * 64), lds);
    grid_sync(grp, root, gen, 4);

    // ---- P4: e3 reduce + bias + sigmoid -> out0 (f32) + cb (bf16) ----
    for (int u = blk; u < 2048; u += NBLK) {
        const int t = u * 256 + tid;
        float s = a.b[2][t & 63];
#pragma unroll
        for (int seg = 0; seg < 16; ++seg)
            s += a.e3part[(size_t)seg * (8192 * 64) + t];
        const float f = 1.f / (1.f + __expf(-s));
        a.out0[t] = f;
        a.cb[t] = (bf16_t)f;
    }
    grid_sync(grp, root, gen, 5);

    // ---- P5: d1 relu(cb @ Wd1) K=64 N=2048 ----
    gemm_tile<128, 128, 64, 64, 1, 1>(
        a.cb, a.t[3], a.b[3], a.ha, nullptr, 2048, 64, 64,
        (xcd * 8 + loc / 16) * 128, (loc % 16) * 128, 0, 0, lds);
    grid_sync(grp, root, gen, 6);

    // ---- P6: d2 relu(ha @ Wd2) K=2048 N=2048 ----
    gemm_tile<128, 128, 64, 64, 1, 1>(
        a.ha, a.t[4], a.b[4], a.hb, nullptr, 2048, 2048, 2048,
        (xcd * 8 + loc / 16) * 128, (loc % 16) * 128, 0, 0, lds);
    grid_sync(grp, root, gen, 7);

    // ---- P7: d3 (hb @ Wd3) -> out1 f32, tiles 64x128 (128 x 8 = 1024) ----
    gemm_tile<64, 128, 32, 64, 0, 2>(
        a.hb, a.t[5], a.b[5], nullptr, a.out1, 1024, 2048, 2048,
        (xcd * 16 + (loc >> 3)) * 64, (loc & 7) * 128, 0, 0, lds);
}

extern "C" void kernel_launch(void* const* d_in, const int* in_sizes, int n_in,
                              void* d_out, int out_size, void* d_ws, size_t ws_size,
                              hipStream_t stream) {
    char* ws = (char*)d_ws;
    size_t off = 0;
    bf16_t* xb  = (bf16_t*)(ws + off); off += (size_t)8192 * 1024 * 2;
    bf16_t* w1t = (bf16_t*)(ws + off); off += (size_t)2048 * 1024 * 2;
    bf16_t* w2t = (bf16_t*)(ws + off); off += (size_t)2048 * 2048 * 2;
    bf16_t* w3t = (bf16_t*)(ws + off); off += (size_t)64   * 2048 * 2;
    bf16_t* w4t = (bf16_t*)(ws + off); off += (size_t)2048 * 64   * 2;
    bf16_t* w5t = (bf16_t*)(ws + off); off += (size_t)2048 * 2048 * 2;
    bf16_t* w6t = (bf16_t*)(ws + off); off += (size_t)1024 * 2048 * 2;
    bf16_t* ha  = (bf16_t*)(ws + off); off += (size_t)8192 * 2048 * 2;
    bf16_t* hb  = (bf16_t*)(ws + off); off += (size_t)8192 * 2048 * 2;
    bf16_t* cb  = (bf16_t*)(ws + off); off += (size_t)8192 * 64   * 2;
    unsigned* bar = (unsigned*)(ws + off); off += 4096;

    FusedArgs a;
    a.x = (const float*)d_in[0];
    a.W[0] = (const float*)d_in[1];  a.b[0] = (const float*)d_in[2];
    a.W[1] = (const float*)d_in[3];  a.b[1] = (const float*)d_in[4];
    a.W[2] = (const float*)d_in[5];  a.b[2] = (const float*)d_in[6];
    a.W[3] = (const float*)d_in[7];  a.b[3] = (const float*)d_in[8];
    a.W[4] = (const float*)d_in[9];  a.b[4] = (const float*)d_in[10];
    a.W[5] = (const float*)d_in[11]; a.b[5] = (const float*)d_in[12];
    a.xb = xb;
    a.t[0] = w1t; a.t[1] = w2t; a.t[2] = w3t;
    a.t[3] = w4t; a.t[4] = w5t; a.t[5] = w6t;
    a.ha = ha; a.hb = hb; a.cb = cb;
    a.e3part = (float*)ha;          // ha dead between e2-consume and d1-write
    a.out0 = (float*)d_out;
    a.out1 = a.out0 + (size_t)8192 * 64;
    a.bar = bar;

    hipMemsetAsync(bar, 0, 4096, stream);   // zero barrier state every launch
    fused<<<dim3(NBLK), dim3(256), 0, stream>>>(a);
}

// Round 7
// 898.335 us; speedup vs baseline: 2.4485x; 2.4485x over previous
//
#include <hip/hip_runtime.h>
#include <hip/hip_bf16.h>
#include <cstdint>
#include <cstddef>

// ---------------------------------------------------------------------------
// AutoEncoder: x[8192,1024] -> enc(1024->2048->2048->64, relu/relu/sigmoid)
//             -> dec(64->2048->2048->1024, relu/relu/none)
// R7: persistent fused kernel, 512 blocks x 512 threads (8 waves).
// R5 failed from accumulator spill (arch 84 + acc 64 = 148 > budget 102);
// R6's register-slimmed rewrite broke correctness (equivalent algebra, so
// suspected compiler scheduling race -> reverted to R5's PROVEN body).
// Fix here: 8 waves/block with 64x32 wave tiles on the same 128x128 block
// tile -> acc 32 AGPR + ~70 arch ~= 100 <= 128 budget of launch_bounds(512,4)
// -> no spill, 2 blocks/CU x 256 CU = 512 resident -> barrier safe.
// MFMA-per-block-barrier unchanged vs R3 (8x8 = 4x16).
// Phases: prep, e1(x2), e2(x2), e3 splitKx8, reduce, d1(x2), d2(x2), d3.
// ---------------------------------------------------------------------------

typedef __bf16 bf16_t;
typedef bf16_t bf16x8 __attribute__((ext_vector_type(8)));
typedef bf16_t bf16x4 __attribute__((ext_vector_type(4)));
typedef float  floatx4 __attribute__((ext_vector_type(4)));

#define NBLK 512
#define NTHR 512

__device__ __forceinline__ void async_cp16(const bf16_t* gp, bf16_t* lp) {
    __builtin_amdgcn_global_load_lds(
        (const __attribute__((address_space(1))) void*)gp,
        (__attribute__((address_space(3))) void*)lp, 16, 0, 0);
}

// Two-level grid barrier: 16 groups x 32 blocks (structure proven in R5).
__device__ __forceinline__ void grid_sync(unsigned* grp, unsigned* root,
                                          unsigned* gen, unsigned s) {
    __syncthreads();
    if (threadIdx.x == 0) {
        __threadfence();
        const int g = blockIdx.x >> 5;   // 16 groups of 32
        unsigned a = __hip_atomic_fetch_add(&grp[g * 16], 1u, __ATOMIC_ACQ_REL,
                                            __HIP_MEMORY_SCOPE_AGENT);
        if (a == 31u) {
            __hip_atomic_store(&grp[g * 16], 0u, __ATOMIC_RELAXED,
                               __HIP_MEMORY_SCOPE_AGENT);
            unsigned r = __hip_atomic_fetch_add(root, 1u, __ATOMIC_ACQ_REL,
                                                __HIP_MEMORY_SCOPE_AGENT);
            if (r == 15u) {
                __hip_atomic_store(root, 0u, __ATOMIC_RELAXED,
                                   __HIP_MEMORY_SCOPE_AGENT);
                __hip_atomic_store(gen, s, __ATOMIC_RELEASE,
                                   __HIP_MEMORY_SCOPE_AGENT);
            }
        }
        while (__hip_atomic_load(gen, __ATOMIC_ACQUIRE,
                                 __HIP_MEMORY_SCOPE_AGENT) < s)
            __builtin_amdgcn_s_sleep(2);
    }
    __syncthreads();
}

// 32x32 transpose+cast tile, flat 512 threads (tx=t&31, ty=t>>5 in [0,16))
__device__ __forceinline__ void trans_tile(const float* __restrict__ in,
                                           bf16_t* __restrict__ out,
                                           int K, int N, int bx, int by,
                                           int tx, int ty,
                                           float (*tile)[33]) {
    const int n0 = bx * 32, k0 = by * 32;
#pragma unroll
    for (int i = 0; i < 32; i += 16)
        tile[ty + i][tx] = in[(size_t)(k0 + ty + i) * N + n0 + tx];
    __syncthreads();
#pragma unroll
    for (int i = 0; i < 32; i += 16)
        out[(size_t)(n0 + ty + i) * K + k0 + tx] = (bf16_t)tile[tx][ty + i];
    __syncthreads();
}

// ---------------------------------------------------------------------------
// One GEMM tile (R5's PROVEN body, generalized to 8 waves + B-staging guard).
// C[m0:+BM, n0:+BN] = act(A[.,ld] @ Bt[.,ld]^T + bias) over K from kz0.
// OMODE bit0: bf16 out, bit1: f32 out, bit2: f32 split-K partial at Cf[pofs+.]
// ACT: 0 none, 1 relu, 2 sigmoid. LDS chunk swizzle -> 0 bank conflicts (R2).
// ---------------------------------------------------------------------------
template<int BM, int BN, int WM, int WN, int ACT, int OMODE>
__device__ void gemm_tile(const bf16_t* __restrict__ A,
                          const bf16_t* __restrict__ Bt,
                          const float* __restrict__ bias,
                          bf16_t* __restrict__ Cb, float* __restrict__ Cf,
                          int N, int K, int ld, int m0, int n0, int kz0,
                          size_t pofs, bf16_t* lds) {
    constexpr int BK = 32;
    constexpr int MI = WM / 16, NI = WN / 16;
    constexpr int WCOLS = BN / WN;
    constexpr int NW = (BM / WM) * (BN / WN);
    static_assert(NW == 8, "8 waves");
    constexpr int TA = BM / 16, TB = BN / 16;      // 64-lane 16B chunks total
    constexpr int A_CPW = (TA + NW - 1) / NW;
    constexpr int B_CPW = (TB + NW - 1) / NW;
    constexpr int ASZ = BM * BK, BSZ = BN * BK;
    bf16_t* As = lds;
    bf16_t* Bs = lds + 2 * ASZ;

    const int tid  = threadIdx.x;
    const int wave = tid >> 6;
    const int lane = tid & 63;
    const int wm0 = (wave / WCOLS) * WM;
    const int wn0 = (wave % WCOLS) * WN;
    const int r15 = lane & 15;
    const int kgc = lane >> 4;

    floatx4 acc[MI][NI];
#pragma unroll
    for (int i = 0; i < MI; ++i)
#pragma unroll
        for (int j = 0; j < NI; ++j)
            acc[i][j] = floatx4{0.f, 0.f, 0.f, 0.f};

    // staging: per-chunk arrays, full formulas (R5 verbatim)
    const bf16_t* a_src[A_CPW];
    int a_dst[A_CPW];
#pragma unroll
    for (int i = 0; i < A_CPW; ++i) {
        const int cbase = (wave * A_CPW + i) * 64;
        const int chunk = cbase + lane;
        const int row = chunk >> 2;
        const int c8  = (((chunk & 3) - (row >> 1)) & 3) * 8;
        a_src[i] = A + (size_t)(m0 + row) * ld + kz0 + c8;
        a_dst[i] = cbase * 8;
    }
    const bf16_t* b_src[B_CPW];
    int b_dst[B_CPW];
#pragma unroll
    for (int i = 0; i < B_CPW; ++i) {
        const int cbase = (wave * B_CPW + i) * 64;
        const int chunk = cbase + lane;
        int row = chunk >> 2;
        if (row >= BN) row = 0;                    // disabled-chunk clamp
        const int c8  = (((chunk & 3) - (row >> 1)) & 3) * 8;
        b_src[i] = Bt + (size_t)(n0 + row) * ld + kz0 + c8;
        b_dst[i] = cbase * 8;
    }
    int a_off[MI], b_off[NI];
#pragma unroll
    for (int i = 0; i < MI; ++i) {
        const int r = wm0 + i * 16 + r15;
        a_off[i] = r * BK + (((kgc + (r >> 1)) & 3) << 3);
    }
#pragma unroll
    for (int j = 0; j < NI; ++j) {
        const int r = wn0 + j * 16 + r15;
        b_off[j] = r * BK + (((kgc + (r >> 1)) & 3) << 3);
    }

    const int nIter = K / BK;
#pragma unroll
    for (int i = 0; i < A_CPW; ++i)
        if (TA == NW * A_CPW || wave * A_CPW + i < TA)
            async_cp16(a_src[i], As + a_dst[i]);
#pragma unroll
    for (int i = 0; i < B_CPW; ++i)
        if (TB == NW * B_CPW || wave * B_CPW + i < TB)
            async_cp16(b_src[i], Bs + b_dst[i]);

    for (int it = 0; it < nIter; ++it) {
        __syncthreads();
        if (it + 1 < nIter) {
            const int kn = (it + 1) * BK;
            const int nb = (it + 1) & 1;
#pragma unroll
            for (int i = 0; i < A_CPW; ++i)
                if (TA == NW * A_CPW || wave * A_CPW + i < TA)
                    async_cp16(a_src[i] + kn, As + nb * ASZ + a_dst[i]);
#pragma unroll
            for (int i = 0; i < B_CPW; ++i)
                if (TB == NW * B_CPW || wave * B_CPW + i < TB)
                    async_cp16(b_src[i] + kn, Bs + nb * BSZ + b_dst[i]);
        }
        const bf16_t* curA = As + (it & 1) * ASZ;
        const bf16_t* curB = Bs + (it & 1) * BSZ;

        bf16x8 af[MI], bfr[NI];
#pragma unroll
        for (int i = 0; i < MI; ++i)
            af[i] = *(const bf16x8*)(curA + a_off[i]);
#pragma unroll
        for (int j = 0; j < NI; ++j)
            bfr[j] = *(const bf16x8*)(curB + b_off[j]);
#pragma unroll
        for (int i = 0; i < MI; ++i)
#pragma unroll
            for (int j = 0; j < NI; ++j)
                acc[i][j] = __builtin_amdgcn_mfma_f32_16x16x32_bf16(
                    af[i], bfr[j], acc[i][j], 0, 0, 0);
    }
    __syncthreads();   // all waves done with LDS before next phase/round

    // epilogue: C/D layout col=lane&15, row=(lane>>4)*4+reg (m89/m91)
    const int row_l = (lane >> 4) * 4;
#pragma unroll
    for (int j = 0; j < NI; ++j) {
        const int n = n0 + wn0 + j * 16 + r15;
        const float bv = (OMODE & 4) ? 0.f : bias[n];
#pragma unroll
        for (int i = 0; i < MI; ++i) {
            const int m = m0 + wm0 + i * 16 + row_l;
#pragma unroll
            for (int r = 0; r < 4; ++r) {
                float f = acc[i][j][r] + bv;
                if (ACT == 1) f = fmaxf(f, 0.f);
                if (ACT == 2) f = 1.f / (1.f + __expf(-f));
                const size_t idx = (size_t)(m + r) * N + n;
                if (OMODE & 1) Cb[idx] = (bf16_t)f;
                if (OMODE & 2) Cf[idx] = f;
                if (OMODE & 4) Cf[pofs + idx] = f;
            }
        }
    }
}

struct FusedArgs {
    const float* x;
    const float* W[6];
    const float* b[6];       // be1,be2,be3,bd1,bd2,bd3
    bf16_t* xb;
    bf16_t* t[6];            // transposed bf16 weights
    bf16_t* ha; bf16_t* hb; bf16_t* cb;
    float* e3part;
    float* out0; float* out1;
    unsigned* bar;           // grp[0..255:16], root@512, gen@528
};

__global__ __launch_bounds__(NTHR, 4) void fused(FusedArgs a) {
    __shared__ bf16_t lds[2 * (128 + 128) * 32];   // 32 KB
    unsigned* grp  = a.bar;
    unsigned* root = a.bar + 512;
    unsigned* gen  = a.bar + 528;
    const int blk = blockIdx.x;
    const int tid = threadIdx.x;

    // ---- P0: prep (x cast: 4096 units; weight transposes: 12544 tiles) ----
    {
        float (*tile)[33] = (float(*)[33])lds;
        const int tx = tid & 31, ty = tid >> 5;
        for (int u = blk; u < 16640; u += NBLK) {
            if (u < 4096) {                      // x: 8192*1024, 4 elts/thread
                const int i = (u * NTHR + tid) * 4;
                const float4 v = *(const float4*)(a.x + i);
                bf16x4 o;
                o[0] = (bf16_t)v.x; o[1] = (bf16_t)v.y;
                o[2] = (bf16_t)v.z; o[3] = (bf16_t)v.w;
                *(bf16x4*)(a.xb + i) = o;
                continue;
            }
            int lb = u - 4096;
            if (lb < 2048)      { trans_tile(a.W[0], a.t[0], 1024, 2048, lb % 64, lb / 64, tx, ty, tile); continue; }
            lb -= 2048;
            if (lb < 4096)      { trans_tile(a.W[1], a.t[1], 2048, 2048, lb % 64, lb / 64, tx, ty, tile); continue; }
            lb -= 4096;
            if (lb < 128)       { trans_tile(a.W[2], a.t[2], 2048, 64,   lb % 2,  lb / 2,  tx, ty, tile); continue; }
            lb -= 128;
            if (lb < 128)       { trans_tile(a.W[3], a.t[3], 64,   2048, lb % 64, lb / 64, tx, ty, tile); continue; }
            lb -= 128;
            if (lb < 4096)      { trans_tile(a.W[4], a.t[4], 2048, 2048, lb % 64, lb / 64, tx, ty, tile); continue; }
            lb -= 4096;
            trans_tile(a.W[5], a.t[5], 2048, 1024, lb % 32, lb / 32, tx, ty, tile);
        }
    }
    grid_sync(grp, root, gen, 1);

    const int xcd = blk & 7;    // stable across +512 rounds (512 % 8 == 0)

    // ---- P1: e1 relu(x @ We1) M=8192 K=1024 N=2048, 1024 tiles / 2 rounds --
#pragma unroll 1
    for (int rd = 0; rd < 2; ++rd) {
        const int loc = (blk + rd * NBLK) >> 3;
        gemm_tile<128, 128, 64, 32, 1, 1>(
            a.xb, a.t[0], a.b[0], a.ha, nullptr, 2048, 1024, 1024,
            (xcd * 8 + loc / 16) * 128, (loc % 16) * 128, 0, 0, lds);
    }
    grid_sync(grp, root, gen, 2);

    // ---- P2: e2 relu(ha @ We2) K=2048 N=2048 ----
#pragma unroll 1
    for (int rd = 0; rd < 2; ++rd) {
        const int loc = (blk + rd * NBLK) >> 3;
        gemm_tile<128, 128, 64, 32, 1, 1>(
            a.ha, a.t[1], a.b[1], a.hb, nullptr, 2048, 2048, 2048,
            (xcd * 8 + loc / 16) * 128, (loc % 16) * 128, 0, 0, lds);
    }
    grid_sync(grp, root, gen, 3);

    // ---- P3: e3 split-K x8 partials: hb @ We3 (K-seg 256) ----
    gemm_tile<128, 64, 32, 32, 0, 4>(
        a.hb, a.t[2], nullptr, nullptr, a.e3part, 64, 256, 2048,
        (blk >> 3) * 128, 0, (blk & 7) * 256,
        (size_t)(blk & 7) * (8192 * 64), lds);
    grid_sync(grp, root, gen, 4);

    // ---- P4: e3 reduce + bias + sigmoid -> out0 (f32) + cb (bf16) ----
    for (int u = blk; u < 1024; u += NBLK) {
        const int t = u * NTHR + tid;
        float s = a.b[2][t & 63];
#pragma unroll
        for (int seg = 0; seg < 8; ++seg)
            s += a.e3part[(size_t)seg * (8192 * 64) + t];
        const float f = 1.f / (1.f + __expf(-s));
        a.out0[t] = f;
        a.cb[t] = (bf16_t)f;
    }
    grid_sync(grp, root, gen, 5);

    // ---- P5: d1 relu(cb @ Wd1) K=64 N=2048 ----
#pragma unroll 1
    for (int rd = 0; rd < 2; ++rd) {
        const int loc = (blk + rd * NBLK) >> 3;
        gemm_tile<128, 128, 64, 32, 1, 1>(
            a.cb, a.t[3], a.b[3], a.ha, nullptr, 2048, 64, 64,
            (xcd * 8 + loc / 16) * 128, (loc % 16) * 128, 0, 0, lds);
    }
    grid_sync(grp, root, gen, 6);

    // ---- P6: d2 relu(ha @ Wd2) K=2048 N=2048 ----
#pragma unroll 1
    for (int rd = 0; rd < 2; ++rd) {
        const int loc = (blk + rd * NBLK) >> 3;
        gemm_tile<128, 128, 64, 32, 1, 1>(
            a.ha, a.t[4], a.b[4], a.hb, nullptr, 2048, 2048, 2048,
            (xcd * 8 + loc / 16) * 128, (loc % 16) * 128, 0, 0, lds);
    }
    grid_sync(grp, root, gen, 7);

    // ---- P7: d3 (hb @ Wd3) -> out1 f32, 512 tiles 128x128 ----
    {
        const int loc = blk >> 3;
        gemm_tile<128, 128, 64, 32, 0, 2>(
            a.hb, a.t[5], a.b[5], nullptr, a.out1, 1024, 2048, 2048,
            (xcd * 8 + loc / 8) * 128, (loc % 8) * 128, 0, 0, lds);
    }
}

extern "C" void kernel_launch(void* const* d_in, const int* in_sizes, int n_in,
                              void* d_out, int out_size, void* d_ws, size_t ws_size,
                              hipStream_t stream) {
    char* ws = (char*)d_ws;
    size_t off = 0;
    bf16_t* xb  = (bf16_t*)(ws + off); off += (size_t)8192 * 1024 * 2;
    bf16_t* w1t = (bf16_t*)(ws + off); off += (size_t)2048 * 1024 * 2;
    bf16_t* w2t = (bf16_t*)(ws + off); off += (size_t)2048 * 2048 * 2;
    bf16_t* w3t = (bf16_t*)(ws + off); off += (size_t)64   * 2048 * 2;
    bf16_t* w4t = (bf16_t*)(ws + off); off += (size_t)2048 * 64   * 2;
    bf16_t* w5t = (bf16_t*)(ws + off); off += (size_t)2048 * 2048 * 2;
    bf16_t* w6t = (bf16_t*)(ws + off); off += (size_t)1024 * 2048 * 2;
    bf16_t* ha  = (bf16_t*)(ws + off); off += (size_t)8192 * 2048 * 2;
    bf16_t* hb  = (bf16_t*)(ws + off); off += (size_t)8192 * 2048 * 2;
    bf16_t* cb  = (bf16_t*)(ws + off); off += (size_t)8192 * 64   * 2;
    unsigned* bar = (unsigned*)(ws + off); off += 4096;

    FusedArgs a;
    a.x = (const float*)d_in[0];
    a.W[0] = (const float*)d_in[1];  a.b[0] = (const float*)d_in[2];
    a.W[1] = (const float*)d_in[3];  a.b[1] = (const float*)d_in[4];
    a.W[2] = (const float*)d_in[5];  a.b[2] = (const float*)d_in[6];
    a.W[3] = (const float*)d_in[7];  a.b[3] = (const float*)d_in[8];
    a.W[4] = (const float*)d_in[9];  a.b[4] = (const float*)d_in[10];
    a.W[5] = (const float*)d_in[11]; a.b[5] = (const float*)d_in[12];
    a.xb = xb;
    a.t[0] = w1t; a.t[1] = w2t; a.t[2] = w3t;
    a.t[3] = w4t; a.t[4] = w5t; a.t[5] = w6t;
    a.ha = ha; a.hb = hb; a.cb = cb;
    a.e3part = (float*)ha;          // ha dead between e2-consume and d1-write
    a.out0 = (float*)d_out;
    a.out1 = a.out0 + (size_t)8192 * 64;
    a.bar = bar;

    hipMemsetAsync(bar, 0, 4096, stream);   // zero barrier state every launch
    fused<<<dim3(NBLK), dim3(NTHR), 0, stream>>>(a);
}